// Round 4
// baseline (382.391 us; speedup 1.0000x reference)
//
#include <hip/hip_runtime.h>
#include <cfloat>

#define NBINS 25
#define THREADS 256
#define GRID1 1024      // pass1 grid; partial width (matches ece_final)
#define ITERS 4         // rows per wave = ITERS*32 = 128; coverage = 4096 waves * 128 = 524288 >= n

// Process one 16-row batch held in registers: lane group (g = lane>>2) owns a row,
// sublane j = lane&3 owns elements {4*(j+4k)+c, k<6} plus element 96+j.
__device__ __forceinline__ void process_batch(const float4 v[7], int j, int lab, bool active,
                                              float* s_cnt, float* s_conf, float* s_acc) {
    // element 96+j lives in component j of v[6] (all 4 lanes loaded the same float4)
    const float x24 = (j == 0) ? v[6].x : (j == 1) ? v[6].y : (j == 2) ? v[6].z : v[6].w;

    // per-lane argmax, ascending index order (first-occurrence ties)
    float m = v[0].x; int mi = 4 * j;
    if (v[0].y > m) { m = v[0].y; mi = 4 * j + 1; }
    if (v[0].z > m) { m = v[0].z; mi = 4 * j + 2; }
    if (v[0].w > m) { m = v[0].w; mi = 4 * j + 3; }
#pragma unroll
    for (int k = 1; k < 6; ++k) {
        const int idx = 4 * (j + 4 * k);
        if (v[k].x > m) { m = v[k].x; mi = idx; }
        if (v[k].y > m) { m = v[k].y; mi = idx + 1; }
        if (v[k].z > m) { m = v[k].z; mi = idx + 2; }
        if (v[k].w > m) { m = v[k].w; mi = idx + 3; }
    }
    if (x24 > m) { m = x24; mi = 96 + j; }
    // group-of-4 argmax reduce; smaller index wins ties
#pragma unroll
    for (int off = 1; off <= 2; off <<= 1) {
        const float om = __shfl_xor(m, off);
        const int   oi = __shfl_xor(mi, off);
        if (om > m || (om == m && oi < mi)) { m = om; mi = oi; }
    }
    // sum of exp(x - m), 25 elements per lane
    float s = __expf(x24 - m);
#pragma unroll
    for (int k = 0; k < 6; ++k) {
        s += __expf(v[k].x - m) + __expf(v[k].y - m) +
             __expf(v[k].z - m) + __expf(v[k].w - m);
    }
#pragma unroll
    for (int off = 1; off <= 2; off <<= 1) s += __shfl_xor(s, off);

    if (j == 0 && active) {
        const float conf = 1.0f / s;                       // exp(m-m)/sumexp
        int bin = (int)ceilf(conf * (float)NBINS) - 1;     // (i/25,(i+1)/25]
        bin = min(max(bin, 0), NBINS - 1);
        const float acc = (mi == lab) ? 1.f : 0.f;
        atomicAdd(&s_cnt[bin], 1.f);
        atomicAdd(&s_conf[bin], conf);
        atomicAdd(&s_acc[bin], acc);
    }
}

// Pass 1: barrier-free, register-resident. 16 independent global loads in flight
// per wave (2 batches x (7 float4 + label)); 16 waves/CU (128-VGPR budget).
__launch_bounds__(THREADS, 4)
__global__ void ece_pass1(const float* __restrict__ logits,
                          const int* __restrict__ labels,
                          float* __restrict__ part, int n) {
    __shared__ float s_cnt[NBINS], s_conf[NBINS], s_acc[NBINS];
    const int t = threadIdx.x;
    if (t < NBINS) { s_cnt[t] = 0.f; s_conf[t] = 0.f; s_acc[t] = 0.f; }
    __syncthreads();

    const int lane = t & 63;
    const int j = lane & 3;    // sublane within 4-lane group
    const int g = lane >> 2;   // group 0..15 -> row within 16-row batch
    const int wid = (int)((blockIdx.x * THREADS + t) >> 6);   // 0..4095

#pragma unroll 1
    for (int it = 0; it < ITERS; ++it) {
        const int rbase = wid * (ITERS * 32) + it * 32;  // wave's 32 contiguous rows
        if (rbase >= n) break;
        const int rowA = rbase + g;
        const int rowB = rbase + 16 + g;
        const int rA = min(rowA, n - 1);
        const int rB = min(rowB, n - 1);
        const float4* pA = reinterpret_cast<const float4*>(logits) + (size_t)rA * 25;
        const float4* pB = reinterpret_cast<const float4*>(logits) + (size_t)rB * 25;

        // ---- load burst: 16 independent requests, no consumer in between ----
        float4 va[7], vb[7];
#pragma unroll
        for (int k = 0; k < 6; ++k) va[k] = pA[j + 4 * k];
        va[6] = pA[24];
#pragma unroll
        for (int k = 0; k < 6; ++k) vb[k] = pB[j + 4 * k];
        vb[6] = pB[24];
        const int labA = labels[rA];
        const int labB = labels[rB];

        // ---- compute ----
        process_batch(va, j, labA, rowA < n, s_cnt, s_conf, s_acc);
        process_batch(vb, j, labB, rowB < n, s_cnt, s_conf, s_acc);
    }

    __syncthreads();
    if (t < NBINS) {
        part[t * GRID1 + blockIdx.x]               = s_cnt[t];
        part[(NBINS + t) * GRID1 + blockIdx.x]     = s_conf[t];
        part[(2 * NBINS + t) * GRID1 + blockIdx.x] = s_acc[t];
    }
}

// Pass 2: reduce 75 x GRID1 partials, then the 25-term ECE sum.
__global__ void ece_final(const float* __restrict__ part, float* __restrict__ out, float n) {
    __shared__ float sacc[3 * NBINS];
    const int t = threadIdx.x;          // 1024 threads = 16 waves
    const int wave = t >> 6, lane = t & 63;
    for (int slot = wave; slot < 3 * NBINS; slot += 16) {
        const float* p = part + slot * GRID1;
        float s = 0.f;
        for (int k = lane; k < GRID1; k += 64) s += p[k];
#pragma unroll
        for (int off = 32; off; off >>= 1) s += __shfl_xor(s, off);
        if (lane == 0) sacc[slot] = s;
    }
    __syncthreads();
    if (t < 64) {
        float term = 0.f;
        if (t < NBINS) {
            const float cnt = sacc[t];
            const float sc  = sacc[NBINS + t];
            const float sa  = sacc[2 * NBINS + t];
            if (cnt > 0.f) {
                const float inv = 1.f / cnt;   // cnt >= 1 -> matches max(counts,1)
                term = fabsf(sc * inv - sa * inv) * (cnt / n);
            }
        }
#pragma unroll
        for (int off = 32; off; off >>= 1) term += __shfl_xor(term, off);
        if (t == 0) out[0] = term;
    }
}

extern "C" void kernel_launch(void* const* d_in, const int* in_sizes, int n_in,
                              void* d_out, int out_size, void* d_ws, size_t ws_size,
                              hipStream_t stream) {
    const float* logits = (const float*)d_in[0];
    const int*   labels = (const int*)d_in[1];
    float* part = (float*)d_ws;         // 75 * GRID1 floats = 300 KB, fully overwritten
    float* out  = (float*)d_out;
    const int n = in_sizes[1];          // number of rows / labels

    ece_pass1<<<GRID1, THREADS, 0, stream>>>(logits, labels, part, n);
    ece_final<<<1, 1024, 0, stream>>>(part, out, (float)n);
}

// Round 6
// 301.910 us; speedup vs baseline: 1.2666x; 1.2666x over previous
//
#include <hip/hip_runtime.h>
#include <cfloat>

#define NBINS 25
#define THREADS 256
#define GRID1 1024      // pass1 grid; partial width (matches ece_final)
#define ITERS 4         // rows per wave = ITERS*32 = 128; 4096 waves * 128 = 524288 >= n

// Compute one row-batch from named registers. j = lane&3, group g owns the row.
// Elements: lane j holds row elements 4*(j+4k)+c in vK (k=0..5), plus v6 = float4 #24
// (elements 96..99, same in all 4 lanes).
#define PROC_BATCH(v0, v1, v2, v3, v4, v5, v6, lab, active)                          \
    do {                                                                              \
        const float x24 = (j == 0) ? (v6).x : (j == 1) ? (v6).y                       \
                         : (j == 2) ? (v6).z : (v6).w;                                \
        float m = (v0).x; int mi = 4 * j;                                             \
        if ((v0).y > m) { m = (v0).y; mi = 4 * j + 1; }                               \
        if ((v0).z > m) { m = (v0).z; mi = 4 * j + 2; }                               \
        if ((v0).w > m) { m = (v0).w; mi = 4 * j + 3; }                               \
        ARGMAX_STEP(v1, 1) ARGMAX_STEP(v2, 2) ARGMAX_STEP(v3, 3)                      \
        ARGMAX_STEP(v4, 4) ARGMAX_STEP(v5, 5)                                         \
        if (x24 > m) { m = x24; mi = 96 + j; }                                        \
        _Pragma("unroll")                                                             \
        for (int off = 1; off <= 2; off <<= 1) {                                      \
            const float om = __shfl_xor(m, off);                                      \
            const int   oi = __shfl_xor(mi, off);                                     \
            if (om > m || (om == m && oi < mi)) { m = om; mi = oi; }                  \
        }                                                                             \
        float s = __expf(x24 - m);                                                    \
        s += __expf((v0).x - m) + __expf((v0).y - m) + __expf((v0).z - m) + __expf((v0).w - m); \
        s += __expf((v1).x - m) + __expf((v1).y - m) + __expf((v1).z - m) + __expf((v1).w - m); \
        s += __expf((v2).x - m) + __expf((v2).y - m) + __expf((v2).z - m) + __expf((v2).w - m); \
        s += __expf((v3).x - m) + __expf((v3).y - m) + __expf((v3).z - m) + __expf((v3).w - m); \
        s += __expf((v4).x - m) + __expf((v4).y - m) + __expf((v4).z - m) + __expf((v4).w - m); \
        s += __expf((v5).x - m) + __expf((v5).y - m) + __expf((v5).z - m) + __expf((v5).w - m); \
        _Pragma("unroll")                                                             \
        for (int off = 1; off <= 2; off <<= 1) s += __shfl_xor(s, off);               \
        if (j == 0 && (active)) {                                                     \
            const float conf = 1.0f / s;                                              \
            int bin = (int)ceilf(conf * (float)NBINS) - 1;                            \
            bin = min(max(bin, 0), NBINS - 1);                                        \
            atomicAdd(&s_cnt[bin], 1.f);                                              \
            atomicAdd(&s_conf[bin], conf);                                            \
            atomicAdd(&s_acc[bin], (mi == (lab)) ? 1.f : 0.f);                        \
        }                                                                             \
    } while (0)

#define ARGMAX_STEP(vk, k)                                                            \
    { const int idx = 4 * (j + 4 * (k));                                              \
      if ((vk).x > m) { m = (vk).x; mi = idx; }                                       \
      if ((vk).y > m) { m = (vk).y; mi = idx + 1; }                                   \
      if ((vk).z > m) { m = (vk).z; mi = idx + 2; }                                   \
      if ((vk).w > m) { m = (vk).w; mi = idx + 3; } }

// Pass 1: barrier-free, register-resident. Named regs + sched_barrier(0) force a
// true 16-deep load burst (no scratch, no load serialization).
__launch_bounds__(THREADS, 4)
__global__ void ece_pass1(const float* __restrict__ logits,
                          const int* __restrict__ labels,
                          float* __restrict__ part, int n) {
    __shared__ float s_cnt[NBINS], s_conf[NBINS], s_acc[NBINS];
    const int t = threadIdx.x;
    if (t < NBINS) { s_cnt[t] = 0.f; s_conf[t] = 0.f; s_acc[t] = 0.f; }
    __syncthreads();

    const int lane = t & 63;
    const int j = lane & 3;    // sublane within 4-lane group
    const int g = lane >> 2;   // group 0..15 -> row within 16-row batch
    const int wid = (int)((blockIdx.x * THREADS + t) >> 6);   // 0..4095

#pragma unroll 1
    for (int it = 0; it < ITERS; ++it) {
        const int rbase = wid * (ITERS * 32) + it * 32;  // wave's 32 rows this iter
        if (rbase >= n) break;
        const int rowA = rbase + g;
        const int rowB = rbase + 16 + g;
        const int rA = min(rowA, n - 1);
        const int rB = min(rowB, n - 1);
        const float4* pA = reinterpret_cast<const float4*>(logits) + (size_t)rA * 25;
        const float4* pB = reinterpret_cast<const float4*>(logits) + (size_t)rB * 25;

        // ---- load burst: 16 independent requests into NAMED registers ----
        float4 a0 = pA[j];      float4 a1 = pA[j + 4];  float4 a2 = pA[j + 8];
        float4 a3 = pA[j + 12]; float4 a4 = pA[j + 16]; float4 a5 = pA[j + 20];
        float4 a6 = pA[24];
        float4 b0 = pB[j];      float4 b1 = pB[j + 4];  float4 b2 = pB[j + 8];
        float4 b3 = pB[j + 12]; float4 b4 = pB[j + 16]; float4 b5 = pB[j + 20];
        float4 b6 = pB[24];
        const int labA = labels[rA];
        const int labB = labels[rB];
        // Pin: no compute may be hoisted above, no load sunk below.
        __builtin_amdgcn_sched_barrier(0);

        // ---- compute ----
        PROC_BATCH(a0, a1, a2, a3, a4, a5, a6, labA, rowA < n);
        PROC_BATCH(b0, b1, b2, b3, b4, b5, b6, labB, rowB < n);
    }

    __syncthreads();
    if (t < NBINS) {
        part[t * GRID1 + blockIdx.x]               = s_cnt[t];
        part[(NBINS + t) * GRID1 + blockIdx.x]     = s_conf[t];
        part[(2 * NBINS + t) * GRID1 + blockIdx.x] = s_acc[t];
    }
}

// Pass 2: reduce 75 x GRID1 partials, then the 25-term ECE sum.
__global__ void ece_final(const float* __restrict__ part, float* __restrict__ out, float n) {
    __shared__ float sacc[3 * NBINS];
    const int t = threadIdx.x;          // 1024 threads = 16 waves
    const int wave = t >> 6, lane = t & 63;
    for (int slot = wave; slot < 3 * NBINS; slot += 16) {
        const float* p = part + slot * GRID1;
        float s = 0.f;
        for (int k = lane; k < GRID1; k += 64) s += p[k];
#pragma unroll
        for (int off = 32; off; off >>= 1) s += __shfl_xor(s, off);
        if (lane == 0) sacc[slot] = s;
    }
    __syncthreads();
    if (t < 64) {
        float term = 0.f;
        if (t < NBINS) {
            const float cnt = sacc[t];
            const float sc  = sacc[NBINS + t];
            const float sa  = sacc[2 * NBINS + t];
            if (cnt > 0.f) {
                const float inv = 1.f / cnt;   // cnt >= 1 -> matches max(counts,1)
                term = fabsf(sc * inv - sa * inv) * (cnt / n);
            }
        }
#pragma unroll
        for (int off = 32; off; off >>= 1) term += __shfl_xor(term, off);
        if (t == 0) out[0] = term;
    }
}

extern "C" void kernel_launch(void* const* d_in, const int* in_sizes, int n_in,
                              void* d_out, int out_size, void* d_ws, size_t ws_size,
                              hipStream_t stream) {
    const float* logits = (const float*)d_in[0];
    const int*   labels = (const int*)d_in[1];
    float* part = (float*)d_ws;         // 75 * GRID1 floats = 300 KB, fully overwritten
    float* out  = (float*)d_out;
    const int n = in_sizes[1];          // number of rows / labels

    ece_pass1<<<GRID1, THREADS, 0, stream>>>(logits, labels, part, n);
    ece_final<<<1, 1024, 0, stream>>>(part, out, (float)n);
}

// Round 8
// 298.101 us; speedup vs baseline: 1.2828x; 1.0128x over previous
//
#include <hip/hip_runtime.h>
#include <cfloat>
#include <stdint.h>

#define NBINS 25
#define THREADS 256
#define GRID1 768          // 3 blocks/CU * 256 CU; also partial-sum width
#define ROWS 64            // rows per chunk; 64*400B = 25.6 KB per buffer
#define CH_F4 (ROWS * 25)  // 1600 float4 per chunk

// Async global->LDS DMA (no VGPR round-trip). LDS dest is HW-computed as
// wave-uniform base + lane*size, which matches our linear layout exactly.
#define GLOAD16(gp, lp)                                                     \
    __builtin_amdgcn_global_load_lds(                                       \
        (const __attribute__((address_space(1))) void*)(gp),                \
        (__attribute__((address_space(3))) void*)(lp), 16, 0, 0)
#define GLOAD4(gp, lp)                                                      \
    __builtin_amdgcn_global_load_lds(                                       \
        (const __attribute__((address_space(1))) void*)(gp),                \
        (__attribute__((address_space(3))) void*)(lp), 4, 0, 0)
#define VMCNT(N) asm volatile("s_waitcnt vmcnt(" #N ")" ::: "memory")

// Per-row compute from named registers. j = lane&3 owns elements 4*(j+4k)+c
// (k=0..5) plus element 96+j (x24).
#define ARGMAX_STEP(vk, k)                                                  \
    { const int idx = 4 * (j + 4 * (k));                                    \
      if ((vk).x > m) { m = (vk).x; mi = idx; }                             \
      if ((vk).y > m) { m = (vk).y; mi = idx + 1; }                         \
      if ((vk).z > m) { m = (vk).z; mi = idx + 2; }                         \
      if ((vk).w > m) { m = (vk).w; mi = idx + 3; } }

__launch_bounds__(THREADS, 3)
__global__ void ece_pass1(const float* __restrict__ logits,
                          const int* __restrict__ labels,
                          float* __restrict__ part, int n) {
    __shared__ __align__(16) float tile[2][ROWS * 100];
    __shared__ int labt[2][ROWS];
    __shared__ float s_cnt[NBINS], s_conf[NBINS], s_acc[NBINS];
    const int t = threadIdx.x;
    if (t < NBINS) { s_cnt[t] = 0.f; s_conf[t] = 0.f; s_acc[t] = 0.f; }
    __syncthreads();   // nothing async outstanding yet; drain harmless

    const int w = t >> 6, l = t & 63;
    const int j = l & 3, g = l >> 2;
    const long totf4 = (long)n * 25;
    const int NCHUNK = (n + ROWS - 1) / ROWS;
    const float4* src = reinterpret_cast<const float4*>(logits);

    // stage: exactly 8 vmem ops per wave (7 data + 1 labels), every wave.
    auto stage = [&](int buf, int c) {
        const long cb = (long)c * CH_F4;
        float* dst = tile[buf];
        const int wb = w * 400;          // this wave's float4 range [wb, wb+400)
#pragma unroll
        for (int k = 0; k < 6; ++k) {
            long gi = cb + wb + k * 64 + l;
            gi = gi < totf4 ? gi : (totf4 - 1);        // clamp: value garbage, slot correct
            GLOAD16(src + gi, dst + (size_t)(wb + k * 64 + l) * 4);
        }
        if (l < 16) {                                   // 16 active lanes in EVERY wave
            long gi = cb + wb + 384 + l;
            gi = gi < totf4 ? gi : (totf4 - 1);
            GLOAD16(src + gi, dst + (size_t)(wb + 384 + l) * 4);
        }
        {   // labels: all 4 waves redundantly DMA the same 64 ints (benign)
            long gi = (long)c * ROWS + l;
            gi = gi < n ? gi : (n - 1);
            GLOAD4(labels + gi, labt[buf] + l);
        }
    };

    int c = blockIdx.x;
    int cur = 0;
    stage(0, c);
    while (true) {
        const int cn = c + GRID1;
        const bool hn = cn < NCHUNK;
        if (hn) { stage(cur ^ 1, cn); VMCNT(8); }   // wait chunk c's 8; next 8 stay in flight
        else    { VMCNT(0); }
        __builtin_amdgcn_s_barrier();               // raw: no vmcnt(0) drain

        // ---- compute chunk c from tile[cur]; NO global loads in this phase ----
        {
            const int r  = w * 16 + g;              // row within chunk
            const int rg = c * ROWS + r;            // global row
            const float* row = tile[cur] + r * 100;
            const float4* r4 = reinterpret_cast<const float4*>(row);
            const float4 v0 = r4[j];      const float4 v1 = r4[j + 4];
            const float4 v2 = r4[j + 8];  const float4 v3 = r4[j + 12];
            const float4 v4 = r4[j + 16]; const float4 v5 = r4[j + 20];
            const float x24 = row[96 + j];
            const int lab = labt[cur][r];

            float m = v0.x; int mi = 4 * j;
            if (v0.y > m) { m = v0.y; mi = 4 * j + 1; }
            if (v0.z > m) { m = v0.z; mi = 4 * j + 2; }
            if (v0.w > m) { m = v0.w; mi = 4 * j + 3; }
            ARGMAX_STEP(v1, 1) ARGMAX_STEP(v2, 2) ARGMAX_STEP(v3, 3)
            ARGMAX_STEP(v4, 4) ARGMAX_STEP(v5, 5)
            if (x24 > m) { m = x24; mi = 96 + j; }
#pragma unroll
            for (int off = 1; off <= 2; off <<= 1) {
                const float om = __shfl_xor(m, off);
                const int   oi = __shfl_xor(mi, off);
                if (om > m || (om == m && oi < mi)) { m = om; mi = oi; }
            }
            float s = __expf(x24 - m);
            s += __expf(v0.x - m) + __expf(v0.y - m) + __expf(v0.z - m) + __expf(v0.w - m);
            s += __expf(v1.x - m) + __expf(v1.y - m) + __expf(v1.z - m) + __expf(v1.w - m);
            s += __expf(v2.x - m) + __expf(v2.y - m) + __expf(v2.z - m) + __expf(v2.w - m);
            s += __expf(v3.x - m) + __expf(v3.y - m) + __expf(v3.z - m) + __expf(v3.w - m);
            s += __expf(v4.x - m) + __expf(v4.y - m) + __expf(v4.z - m) + __expf(v4.w - m);
            s += __expf(v5.x - m) + __expf(v5.y - m) + __expf(v5.z - m) + __expf(v5.w - m);
#pragma unroll
            for (int off = 1; off <= 2; off <<= 1) s += __shfl_xor(s, off);

            if (j == 0 && rg < n) {
                const float conf = 1.0f / s;                       // exp(m-m)/sumexp
                int bin = (int)ceilf(conf * (float)NBINS) - 1;     // (i/25,(i+1)/25]
                bin = min(max(bin, 0), NBINS - 1);
                atomicAdd(&s_cnt[bin], 1.f);
                atomicAdd(&s_conf[bin], conf);
                atomicAdd(&s_acc[bin], (mi == lab) ? 1.f : 0.f);
            }
        }
        __builtin_amdgcn_s_barrier();   // all done reading tile[cur] before re-staging it
        if (!hn) break;
        cur ^= 1; c = cn;
    }

    __syncthreads();
    if (t < NBINS) {
        part[t * GRID1 + blockIdx.x]               = s_cnt[t];
        part[(NBINS + t) * GRID1 + blockIdx.x]     = s_conf[t];
        part[(2 * NBINS + t) * GRID1 + blockIdx.x] = s_acc[t];
    }
}

// Pass 2: reduce 75 x GRID1 partials, then the 25-term ECE sum.
__global__ void ece_final(const float* __restrict__ part, float* __restrict__ out, float n) {
    __shared__ float sacc[3 * NBINS];
    const int t = threadIdx.x;          // 1024 threads = 16 waves
    const int wave = t >> 6, lane = t & 63;
    for (int slot = wave; slot < 3 * NBINS; slot += 16) {
        const float* p = part + slot * GRID1;
        float s = 0.f;
        for (int k = lane; k < GRID1; k += 64) s += p[k];
#pragma unroll
        for (int off = 32; off; off >>= 1) s += __shfl_xor(s, off);
        if (lane == 0) sacc[slot] = s;
    }
    __syncthreads();
    if (t < 64) {
        float term = 0.f;
        if (t < NBINS) {
            const float cnt = sacc[t];
            const float sc  = sacc[NBINS + t];
            const float sa  = sacc[2 * NBINS + t];
            if (cnt > 0.f) {
                const float inv = 1.f / cnt;   // cnt >= 1 -> matches max(counts,1)
                term = fabsf(sc * inv - sa * inv) * (cnt / n);
            }
        }
#pragma unroll
        for (int off = 32; off; off >>= 1) term += __shfl_xor(term, off);
        if (t == 0) out[0] = term;
    }
}

extern "C" void kernel_launch(void* const* d_in, const int* in_sizes, int n_in,
                              void* d_out, int out_size, void* d_ws, size_t ws_size,
                              hipStream_t stream) {
    const float* logits = (const float*)d_in[0];
    const int*   labels = (const int*)d_in[1];
    float* part = (float*)d_ws;         // 75 * GRID1 floats, fully overwritten each call
    float* out  = (float*)d_out;
    const int n = in_sizes[1];          // number of rows / labels

    ece_pass1<<<GRID1, THREADS, 0, stream>>>(logits, labels, part, n);
    ece_final<<<1, 1024, 0, stream>>>(part, out, (float)n);
}